// Round 7
// baseline (467.552 us; speedup 1.0000x reference)
//
#include <hip/hip_runtime.h>
#include <hip/hip_bf16.h>
#include <math.h>

#define EMBED 1024
#define KD 64
#define NH 16
#define SEQ 2048
#define BATCH 4
#define BH (BATCH * NH)     // 64
#define NTOK ((size_t)BH * SEQ * KD)   // 8,388,608

typedef float4 f4;
typedef unsigned short u16;
typedef __attribute__((ext_vector_type(8))) short v8s;   // 8 bf16 (MFMA A/B frag)
typedef __attribute__((ext_vector_type(4))) float v4f;   // MFMA C/D frag

__device__ __forceinline__ u16 f2bf(float f) {
    unsigned u = __float_as_uint(f);
    unsigned r = (u + 0x7fffu + ((u >> 16) & 1u)) >> 16;
    return (u16)r;
}
__device__ __forceinline__ float bf2f(u16 h) {
    return __uint_as_float(((unsigned)h) << 16);
}

// async global->LDS, 16B/lane. LDS dest = wave-uniform base + lane*16.
__device__ __forceinline__ void gload_lds16(const void* g, void* l) {
    __builtin_amdgcn_global_load_lds(
        (const __attribute__((address_space(1))) unsigned int*)g,
        (__attribute__((address_space(3))) unsigned int*)l, 16, 0, 0);
}

// ------------------------------------------------------------------
// Fused converter: blocks [0,8192) -> x split; [8192,11264) -> qkv W
// (transposed, Q scaled by 0.125*log2e); [11264,12288) -> out W.
// ------------------------------------------------------------------
__global__ __launch_bounds__(256)
void convert_all_kernel(const float* __restrict__ x,
                        const float* __restrict__ wq, const float* __restrict__ wk,
                        const float* __restrict__ wv, const float* __restrict__ w,
                        u16* __restrict__ xh, u16* __restrict__ xl,
                        u16* __restrict__ Wth, u16* __restrict__ Wtl,
                        u16* __restrict__ OWth, u16* __restrict__ OWtl)
{
    int b = blockIdx.x;
    if (b < 8192) {
        size_t i = ((size_t)b * 256 + threadIdx.x) * 4;
        f4 v = *(const f4*)(x + i);
        u16 h0 = f2bf(v.x), h1 = f2bf(v.y), h2 = f2bf(v.z), h3 = f2bf(v.w);
        u16 l0 = f2bf(v.x - bf2f(h0)), l1 = f2bf(v.y - bf2f(h1));
        u16 l2 = f2bf(v.z - bf2f(h2)), l3 = f2bf(v.w - bf2f(h3));
        uint2 H, L;
        H.x = (unsigned)h0 | ((unsigned)h1 << 16);
        H.y = (unsigned)h2 | ((unsigned)h3 << 16);
        L.x = (unsigned)l0 | ((unsigned)l1 << 16);
        L.y = (unsigned)l2 | ((unsigned)l3 << 16);
        *(uint2*)(xh + i) = H;
        *(uint2*)(xl + i) = L;
    } else if (b < 8192 + 3072) {
        int n = b - 8192;                     // 0..3071
        int mat = n >> 10, nin = n & 1023, h = nin >> 6, c = nin & 63;
        const float* __restrict__ ws = (mat == 0) ? wq : (mat == 1) ? wk : wv;
        float sc = (mat == 0) ? (0.125f * 1.4426950408889634f) : 1.0f;
        for (int d = threadIdx.x; d < EMBED; d += 256) {
            float f = ws[((size_t)h * EMBED + d) * KD + c] * sc;
            u16 hi = f2bf(f);
            u16 lo = f2bf(f - bf2f(hi));
            Wth[(size_t)n * EMBED + d] = hi;
            Wtl[(size_t)n * EMBED + d] = lo;
        }
    } else {
        int n = b - 11264;                    // 0..1023
        for (int k = threadIdx.x; k < EMBED; k += 256) {
            float f = w[(size_t)k * EMBED + n];
            u16 hi = f2bf(f);
            u16 lo = f2bf(f - bf2f(hi));
            OWth[(size_t)n * EMBED + k] = hi;
            OWtl[(size_t)n * EMBED + k] = lo;
        }
    }
}

// ------------------------------------------------------------------
// Kernel: Q/K projection, MFMA bf16 3-term (unchanged).
// ------------------------------------------------------------------
__global__ __launch_bounds__(256)
void qk_mfma_kernel(const u16* __restrict__ xh, const u16* __restrict__ xl,
                    const u16* __restrict__ Wth, const u16* __restrict__ Wtl,
                    u16* __restrict__ Qhi, u16* __restrict__ Qlo,
                    u16* __restrict__ Khi, u16* __restrict__ Klo)
{
    __shared__ u16 sAh[128 * 64];
    __shared__ u16 sAl[128 * 64];
    __shared__ u16 sBh[128 * 64];
    __shared__ u16 sBl[128 * 64];
    const int tid = threadIdx.x;
    const int lane = tid & 63, wid = tid >> 6;
    const int lm = lane & 15, lq = lane >> 4;
    const int wm = wid & 1, wn = wid >> 1;
    const int m0 = blockIdx.y * 128;
    const int n0 = blockIdx.x * 128;     // 0..2047 (Q then K)

    v4f acc[4][4];
#pragma unroll
    for (int mt = 0; mt < 4; ++mt)
#pragma unroll
        for (int nt = 0; nt < 4; ++nt)
            acc[mt][nt] = (v4f){0.f, 0.f, 0.f, 0.f};

    const int srow = wid * 32 + (lane >> 3);
    const int sblk = (lane & 7) ^ (lane >> 3);

    for (int k0 = 0; k0 < EMBED; k0 += 64) {
        __syncthreads();
#pragma unroll
        for (int i = 0; i < 4; ++i) {
            int row = srow + i * 8;
            size_t gA = (((size_t)(m0 + row)) << 10) + k0 + sblk * 8;
            size_t gB = (((size_t)(n0 + row)) << 10) + k0 + sblk * 8;
            int lo = (wid * 32 + i * 8) * 128;
            gload_lds16((const char*)xh + gA * 2, (char*)sAh + lo);
            gload_lds16((const char*)Wth + gB * 2, (char*)sBh + lo);
            gload_lds16((const char*)xl + gA * 2, (char*)sAl + lo);
            gload_lds16((const char*)Wtl + gB * 2, (char*)sBl + lo);
        }
        asm volatile("s_waitcnt vmcnt(0)" ::: "memory");
        __syncthreads();

#pragma unroll
        for (int kks = 0; kks < 2; ++kks) {
            const int ba = ((kks * 4 + lq) ^ (lm & 7)) * 8;
            v8s ah[4], bh[4], al[4], bl[4];
#pragma unroll
            for (int t = 0; t < 4; ++t) {
                int ra = wm * 64 + t * 16 + lm;
                int rb = wn * 64 + t * 16 + lm;
                ah[t] = *(const v8s*)&sAh[ra * 64 + ba];
                bh[t] = *(const v8s*)&sBh[rb * 64 + ba];
                al[t] = *(const v8s*)&sAl[ra * 64 + ba];
                bl[t] = *(const v8s*)&sBl[rb * 64 + ba];
            }
#pragma unroll
            for (int mt = 0; mt < 4; ++mt)
#pragma unroll
                for (int nt = 0; nt < 4; ++nt) {
                    acc[mt][nt] = __builtin_amdgcn_mfma_f32_16x16x32_bf16(ah[mt], bh[nt], acc[mt][nt], 0, 0, 0);
                    acc[mt][nt] = __builtin_amdgcn_mfma_f32_16x16x32_bf16(ah[mt], bl[nt], acc[mt][nt], 0, 0, 0);
                    acc[mt][nt] = __builtin_amdgcn_mfma_f32_16x16x32_bf16(al[mt], bh[nt], acc[mt][nt], 0, 0, 0);
                }
        }
    }

    const int mrow0 = m0 + wm * 64;
    const int ncol0 = n0 + wn * 64;
    const bool isQ = (n0 < 1024);
#pragma unroll
    for (int mt = 0; mt < 4; ++mt) {
        int sbase = mrow0 + mt * 16 + lq * 4;
        int bb = sbase >> 11, sB = sbase & 2047;
#pragma unroll
        for (int nt = 0; nt < 4; ++nt) {
            int nin = (ncol0 + nt * 16 + lm) & 1023;
            int h = nin >> 6, cc = nin & 63;
            int bh_ = bb * NH + h;
#pragma unroll
            for (int r = 0; r < 4; ++r) {
                int s = sB + r;
                float f = acc[mt][nt][r];
                u16 hi = f2bf(f);
                u16 lo = f2bf(f - bf2f(hi));
                if (isQ) {
                    size_t a = ((size_t)bh_ * SEQ + s) * KD + cc;
                    Qhi[a] = hi;
                    Qlo[a] = lo;
                } else {
                    int ccp = ((((cc >> 3) ^ (s & 7)) << 3) | (cc & 7));
                    size_t a = ((size_t)bh_ * SEQ + s) * KD + ccp;
                    Khi[a] = hi;
                    Klo[a] = lo;
                }
            }
        }
    }
}

// ------------------------------------------------------------------
// Kernel: V projection, MFMA bf16 1-term (unchanged).
// ------------------------------------------------------------------
__global__ __launch_bounds__(256)
void v_mfma_kernel(const u16* __restrict__ xh,
                   const u16* __restrict__ Wth,
                   u16* __restrict__ Vt)
{
    __shared__ u16 sAh[128 * 64];
    __shared__ u16 sBh[128 * 64];
    const int tid = threadIdx.x;
    const int lane = tid & 63, wid = tid >> 6;
    const int lm = lane & 15, lq = lane >> 4;
    const int wm = wid & 1, wn = wid >> 1;
    const int m0 = blockIdx.y * 128;
    const int n0g = 2048 + blockIdx.x * 128;   // V rows of Wt

    v4f acc[4][4];
#pragma unroll
    for (int mt = 0; mt < 4; ++mt)
#pragma unroll
        for (int nt = 0; nt < 4; ++nt)
            acc[mt][nt] = (v4f){0.f, 0.f, 0.f, 0.f};

    const int srow = wid * 32 + (lane >> 3);
    const int sblk = (lane & 7) ^ (lane >> 3);

    for (int k0 = 0; k0 < EMBED; k0 += 64) {
        __syncthreads();
#pragma unroll
        for (int i = 0; i < 4; ++i) {
            int row = srow + i * 8;
            size_t gA = (((size_t)(m0 + row)) << 10) + k0 + sblk * 8;
            size_t gB = (((size_t)(n0g + row)) << 10) + k0 + sblk * 8;
            int lo = (wid * 32 + i * 8) * 128;
            gload_lds16((const char*)xh + gA * 2, (char*)sAh + lo);
            gload_lds16((const char*)Wth + gB * 2, (char*)sBh + lo);
        }
        asm volatile("s_waitcnt vmcnt(0)" ::: "memory");
        __syncthreads();

#pragma unroll
        for (int kks = 0; kks < 2; ++kks) {
            const int ba = ((kks * 4 + lq) ^ (lm & 7)) * 8;
            v8s ah[4], bh[4];
#pragma unroll
            for (int t = 0; t < 4; ++t) {
                int ra = wm * 64 + t * 16 + lm;
                int rb = wn * 64 + t * 16 + lm;
                ah[t] = *(const v8s*)&sAh[ra * 64 + ba];
                bh[t] = *(const v8s*)&sBh[rb * 64 + ba];
            }
#pragma unroll
            for (int mt = 0; mt < 4; ++mt)
#pragma unroll
                for (int nt = 0; nt < 4; ++nt)
                    acc[mt][nt] = __builtin_amdgcn_mfma_f32_16x16x32_bf16(ah[mt], bh[nt], acc[mt][nt], 0, 0, 0);
        }
    }

    const int mrow0 = m0 + wm * 64;
    const int ncol0 = n0g + wn * 64;
#pragma unroll
    for (int mt = 0; mt < 4; ++mt) {
        int sbase = mrow0 + mt * 16 + lq * 4;
        int bb = sbase >> 11, s = sbase & 2047;
#pragma unroll
        for (int nt = 0; nt < 4; ++nt) {
            int nin = (ncol0 + nt * 16 + lm) & 1023;
            int h = nin >> 6, cc = nin & 63;
            int bh_ = bb * NH + h;
            size_t a = ((size_t)bh_ * KD + cc) * SEQ
                     + (size_t)(((((s >> 3) ^ (cc & 7)) << 3)) | (s & 7));
            uint2 u;
            u.x = (unsigned)f2bf(acc[mt][nt][0]) | ((unsigned)f2bf(acc[mt][nt][1]) << 16);
            u.y = (unsigned)f2bf(acc[mt][nt][2]) | ((unsigned)f2bf(acc[mt][nt][3]) << 16);
            *(uint2*)(Vt + a) = u;
        }
    }
}

// ------------------------------------------------------------------
// Kernel: flash attention, 8-wave.
// R6: (a) V read DIRECTLY from global (L2-resident per head, shared by
// 16 same-XCD blocks) into regs — deletes the sVt LDS plane, its DMA,
// and 8 ds_read_b128/tile; PV B-operand is a contiguous 16B of the
// pre-swizzled Vt: vbase[kk2][nt] + t0.
// (b) Freed plane -> TRIPLE-buffered K (3x16KB + 16KB sPs = 64KB,
// still 2 blocks/CU — deliberately not 48KB/3 blocks: 4 blocks/CU of
// work would split 3+1, the R0 tail lesson). Stage t+2 each tile; V
// loads issued BEFORE the stage so the compiler's PV wait is a counted
// vmcnt, not a full drain. Explicit vmcnt(2) before the barrier
// publishes each wave's K rows cross-wave (FIFO-verified for all
// iterations incl. the un-staged tail tiles).
// ------------------------------------------------------------------
__global__ __launch_bounds__(512)
void attn_kernel(const u16* __restrict__ Qhi, const u16* __restrict__ Qlo,
                 const u16* __restrict__ Khi, const u16* __restrict__ Klo,
                 const u16* __restrict__ Vt,  u16* __restrict__ headsb)
{
    __shared__ u16 sK[3][2][64 * 64];    // [buf][Khi,Klo] 8KB planes
    __shared__ u16 sPs[128 * 64];        // 16 KB; swizzled, wave-private rows

    const int tid = threadIdx.x;
    const int lane = tid & 63, wid = tid >> 6;        // wid 0..7
    const int lm = lane & 15, lq = lane >> 4;
    const int psw = (lm & 7) << 3;   // sPs XOR swizzle (u16 units)
    const int rowbase = (wid >> 1) * 32 + (wid & 1) * 16;   // 0..112, step 16
    const int q0 = blockIdx.y * 128;
    const int bh = blockIdx.x;
    const int bb = bh >> 4, h = bh & 15;

    // Q fragments resident: q-rows q0 + rowbase + lm
    v8s qh[2], ql[2];
#pragma unroll
    for (int kk = 0; kk < 2; ++kk) {
        size_t g = ((size_t)bh * SEQ + q0 + rowbase + lm) * KD + kk * 32 + lq * 8;
        qh[kk] = *(const v8s*)(Qhi + g);
        ql[kk] = *(const v8s*)(Qlo + g);
    }

    v8s vones;
#pragma unroll
    for (int i = 0; i < 8; ++i) vones[i] = (short)0x3F80;   // bf16 1.0
    const v4f z4 = (v4f){0.f, 0.f, 0.f, 0.f};               // hoisted zero C

    // bpermute source-lane addrs: alpha for ctx row lq*4+r lives at lane
    // (same lq group) with lm = lq*4+r
    int bpaddr[4];
#pragma unroll
    for (int r = 0; r < 4; ++r)
        bpaddr[r] = (((lane & 48) | (lq * 4 + r)) << 2);

    // V direct-read base pointers (t0-invariant): B-operand for PV
    // (hd = nt*16+lm, keys kk2*32 + lq*8 .. +8, pre-swizzled layout)
    const u16* vbase[2][4];
#pragma unroll
    for (int kk2 = 0; kk2 < 2; ++kk2)
#pragma unroll
        for (int nt = 0; nt < 4; ++nt) {
            int hd = nt * 16 + lm;
            vbase[kk2][nt] = Vt + ((size_t)bh * KD + hd) * SEQ
                           + (((kk2 * 4 + lq) ^ (hd & 7)) << 3);
        }

    v4f ctx[4], lcol;
    float mrun = -INFINITY;
    lcol = (v4f){0.f, 0.f, 0.f, 0.f};
#pragma unroll
    for (int nt = 0; nt < 4; ++nt)
        ctx[nt] = (v4f){0.f, 0.f, 0.f, 0.f};

    const size_t kbase = (size_t)bh * SEQ * KD;
    const char* gKh = (const char*)(Khi + kbase);
    const char* gKl = (const char*)(Klo + kbase);
    const int ko = wid * 1024;                      // LDS byte offset per wave

    // stage key-tile starting at key t0s into K buffer buf
    auto STAGE = [&](int t0s, int buf) {
        int kb = t0s * 128 + ko + lane * 16;        // K bytes (128B per key row)
        gload_lds16(gKh + kb, (char*)&sK[buf][0][0] + ko);
        gload_lds16(gKl + kb, (char*)&sK[buf][1][0] + ko);
    };

    STAGE(0, 0);
    STAGE(64, 1);

    int cur = 0;
    for (int t0 = 0; t0 < SEQ; t0 += 64) {
        // own tile-t K loads done (2 newest = next tile's stage, still ok);
        // then publish cross-wave.
        asm volatile("s_waitcnt vmcnt(2)" ::: "memory");
        __syncthreads();

        // ---- V loads for THIS tile, direct global->reg (L2 hit).
        // Issued before the stage so PV's implicit wait is counted.
        v8s vb[2][4];
#pragma unroll
        for (int kk2 = 0; kk2 < 2; ++kk2)
#pragma unroll
            for (int nt = 0; nt < 4; ++nt)
                vb[kk2][nt] = *(const v8s*)(vbase[kk2][nt] + t0);

        // ---- prefetch tile t+2 into the buffer QK(t-1) just vacated
        if (t0 + 128 < SEQ) {
            int nb = cur + 2; if (nb >= 3) nb -= 3;
            STAGE(t0 + 128, nb);
        }

        const u16* sKhi = &sK[cur][0][0];
        const u16* sKlo = &sK[cur][1][0];

        // ---- scores = K·Q^T: sc[kt], rows=keys, cols=qrows (this wave's group)
        v4f sc[4];
        __builtin_amdgcn_s_setprio(1);
#pragma unroll
        for (int kt = 0; kt < 4; ++kt) {
            int key = kt * 16 + lm;
            int blk = lq ^ (key & 7);                 // kk = 0
            v8s kh16 = *(const v8s*)&sKhi[key * 64 + blk * 8];
            v8s kl16 = *(const v8s*)&sKlo[key * 64 + blk * 8];
            sc[kt] = __builtin_amdgcn_mfma_f32_16x16x32_bf16(kh16, qh[0], z4, 0, 0, 0);
            sc[kt] = __builtin_amdgcn_mfma_f32_16x16x32_bf16(kl16, qh[0], sc[kt], 0, 0, 0);
            sc[kt] = __builtin_amdgcn_mfma_f32_16x16x32_bf16(kh16, ql[0], sc[kt], 0, 0, 0);
        }
#pragma unroll
        for (int kt = 0; kt < 4; ++kt) {
            int key = kt * 16 + lm;
            int blk = (4 + lq) ^ (key & 7);           // kk = 1
            v8s kh16 = *(const v8s*)&sKhi[key * 64 + blk * 8];
            v8s kl16 = *(const v8s*)&sKlo[key * 64 + blk * 8];
            sc[kt] = __builtin_amdgcn_mfma_f32_16x16x32_bf16(kh16, qh[1], sc[kt], 0, 0, 0);
            sc[kt] = __builtin_amdgcn_mfma_f32_16x16x32_bf16(kl16, qh[1], sc[kt], 0, 0, 0);
            sc[kt] = __builtin_amdgcn_mfma_f32_16x16x32_bf16(kh16, ql[1], sc[kt], 0, 0, 0);
        }
        __builtin_amdgcn_s_setprio(0);

        // ---- online softmax (base-2): lane owns q-row lm; 16 vals =
        // keys kt*16 + lq*4 + r
        float m0v = fmaxf(fmaxf(fmaxf(sc[0][0], sc[0][1]), sc[0][2]), sc[0][3]);
        float m1v = fmaxf(fmaxf(fmaxf(sc[1][0], sc[1][1]), sc[1][2]), sc[1][3]);
        float m2v = fmaxf(fmaxf(fmaxf(sc[2][0], sc[2][1]), sc[2][2]), sc[2][3]);
        float m3v = fmaxf(fmaxf(fmaxf(sc[3][0], sc[3][1]), sc[3][2]), sc[3][3]);
        float mx = fmaxf(fmaxf(fmaxf(m0v, m1v), m2v), m3v);
        mx = fmaxf(mx, __shfl_xor(mx, 16));
        mx = fmaxf(mx, __shfl_xor(mx, 32));

        // ---- T13 defer-max: skip rescale when nothing grew past mrun+8.
        if (!__all((int)(mx <= mrun + 8.f))) {
            float mold = mrun;
            float mnew = fmaxf(mold, mx);
            float a = __builtin_amdgcn_exp2f(mold - mnew);
            mrun = mnew;
#pragma unroll
            for (int r = 0; r < 4; ++r) {
                float ar = __uint_as_float(
                    __builtin_amdgcn_ds_bpermute(bpaddr[r], __float_as_uint(a)));
                lcol[r] *= ar;
#pragma unroll
                for (int nt = 0; nt < 4; ++nt)
                    ctx[nt][r] *= ar;
            }
        }

        // ---- p, truncate-pack, b64 write: 4 consecutive keys per quad
        {
            u16* pbase = &sPs[(rowbase + lm) * 64];
#pragma unroll
            for (int kt = 0; kt < 4; ++kt) {
                unsigned u0 = __float_as_uint(__builtin_amdgcn_exp2f(sc[kt][0] - mrun));
                unsigned u1 = __float_as_uint(__builtin_amdgcn_exp2f(sc[kt][1] - mrun));
                unsigned u2 = __float_as_uint(__builtin_amdgcn_exp2f(sc[kt][2] - mrun));
                unsigned u3 = __float_as_uint(__builtin_amdgcn_exp2f(sc[kt][3] - mrun));
                uint2 pk;
                pk.x = __builtin_amdgcn_perm(u1, u0, 0x07060302);  // [bf(p1)|bf(p0)]
                pk.y = __builtin_amdgcn_perm(u3, u2, 0x07060302);
                *(uint2*)&pbase[(kt * 16 + lq * 4) ^ psw] = pk;
            }
        }
        // same-wave ds_write -> ds_read (compiler inserts lgkm wait);
        // P rows are wave-private, no barrier needed.

        // ---- PV (+ ones column accumulates l); B operands from regs (vb)
        __builtin_amdgcn_s_setprio(1);
#pragma unroll
        for (int kk2 = 0; kk2 < 2; ++kk2) {
            v8s a = *(const v8s*)&sPs[(rowbase + lm) * 64 + ((kk2 * 32 + lq * 8) ^ psw)];
#pragma unroll
            for (int nt = 0; nt < 4; ++nt)
                ctx[nt] = __builtin_amdgcn_mfma_f32_16x16x32_bf16(a, vb[kk2][nt], ctx[nt], 0, 0, 0);
            lcol = __builtin_amdgcn_mfma_f32_16x16x32_bf16(a, vones, lcol, 0, 0, 0);
        }
        __builtin_amdgcn_s_setprio(0);

        cur = (cur == 2) ? 0 : cur + 1;
    }

    // ---- epilogue: heads[bb][row][h*64+hd] = ctx / l (bf16)
#pragma unroll
    for (int r = 0; r < 4; ++r) {
        int row = q0 + rowbase + lq * 4 + r;
        float inv = 1.0f / lcol[r];
        u16* dst = headsb + ((size_t)bb * SEQ + row) * EMBED + h * KD;
#pragma unroll
        for (int nt = 0; nt < 4; ++nt)
            dst[nt * 16 + lm] = f2bf(ctx[nt][r] * inv);
    }
}

// ------------------------------------------------------------------
// Kernel: output projection, MFMA bf16 2-term (unchanged).
// ------------------------------------------------------------------
__global__ __launch_bounds__(256)
void out_mfma_kernel(const u16* __restrict__ headsb,
                     const u16* __restrict__ OWth, const u16* __restrict__ OWtl,
                     float* __restrict__ out)
{
    __shared__ u16 sA[128 * 64];
    __shared__ u16 sBh[128 * 64];
    __shared__ u16 sBl[128 * 64];
    const int tid = threadIdx.x;
    const int lane = tid & 63, wid = tid >> 6;
    const int lm = lane & 15, lq = lane >> 4;
    const int wm = wid & 1, wn = wid >> 1;
    const int m0 = blockIdx.y * 128;
    const int n0 = blockIdx.x * 128;

    v4f acc[4][4];
#pragma unroll
    for (int mt = 0; mt < 4; ++mt)
#pragma unroll
        for (int nt = 0; nt < 4; ++nt)
            acc[mt][nt] = (v4f){0.f, 0.f, 0.f, 0.f};

    const int srow = wid * 32 + (lane >> 3);
    const int sblk = (lane & 7) ^ (lane >> 3);

    for (int k0 = 0; k0 < EMBED; k0 += 64) {
        __syncthreads();
#pragma unroll
        for (int i = 0; i < 4; ++i) {
            int row = srow + i * 8;
            size_t gA = (((size_t)(m0 + row)) << 10) + k0 + sblk * 8;
            size_t gB = (((size_t)(n0 + row)) << 10) + k0 + sblk * 8;
            int lo = (wid * 32 + i * 8) * 128;
            gload_lds16((const char*)headsb + gA * 2, (char*)sA + lo);
            gload_lds16((const char*)OWth + gB * 2, (char*)sBh + lo);
            gload_lds16((const char*)OWtl + gB * 2, (char*)sBl + lo);
        }
        asm volatile("s_waitcnt vmcnt(0)" ::: "memory");
        __syncthreads();

#pragma unroll
        for (int kks = 0; kks < 2; ++kks) {
            const int ba = ((kks * 4 + lq) ^ (lm & 7)) * 8;
            v8s ah[4], bh[4], bl[4];
#pragma unroll
            for (int t = 0; t < 4; ++t) {
                int ra = wm * 64 + t * 16 + lm;
                int rb = wn * 64 + t * 16 + lm;
                ah[t] = *(const v8s*)&sA[ra * 64 + ba];
                bh[t] = *(const v8s*)&sBh[rb * 64 + ba];
                bl[t] = *(const v8s*)&sBl[rb * 64 + ba];
            }
#pragma unroll
            for (int mt = 0; mt < 4; ++mt)
#pragma unroll
                for (int nt = 0; nt < 4; ++nt) {
                    acc[mt][nt] = __builtin_amdgcn_mfma_f32_16x16x32_bf16(ah[mt], bh[nt], acc[mt][nt], 0, 0, 0);
                    acc[mt][nt] = __builtin_amdgcn_mfma_f32_16x16x32_bf16(ah[mt], bl[nt], acc[mt][nt], 0, 0, 0);
                }
        }
    }

    const int mrow0 = m0 + wm * 64;
    const int ncol0 = n0 + wn * 64;
#pragma unroll
    for (int mt = 0; mt < 4; ++mt) {
        int sbase = mrow0 + mt * 16 + lq * 4;
#pragma unroll
        for (int nt = 0; nt < 4; ++nt) {
            int n = ncol0 + nt * 16 + lm;
#pragma unroll
            for (int r = 0; r < 4; ++r)
                out[(size_t)(sbase + r) * EMBED + n] = acc[mt][nt][r];
        }
    }
}

// ------------------------------------------------------------------
extern "C" void kernel_launch(void* const* d_in, const int* in_sizes, int n_in,
                              void* d_out, int out_size, void* d_ws, size_t ws_size,
                              hipStream_t stream) {
    const float* x  = (const float*)d_in[0];
    const float* wq = (const float*)d_in[1];
    const float* wk = (const float*)d_in[2];
    const float* wv = (const float*)d_in[3];
    const float* w  = (const float*)d_in[4];
    float* out = (float*)d_out;

    u16* Qhi = (u16*)d_ws;
    u16* Qlo = Qhi + NTOK;
    u16* Khi = Qlo + NTOK;
    u16* Klo = Khi + NTOK;
    u16* Vt  = Klo + NTOK;
    u16* xh  = Vt + NTOK;                 // [8192][1024]
    u16* xl  = xh + NTOK;
    u16* Wth = xl + NTOK;                 // [3072][1024]
    u16* Wtl = Wth + (size_t)3072 * 1024;
    u16* OWth = Wtl + (size_t)3072 * 1024;  // [1024][1024]
    u16* OWtl = OWth + (size_t)1024 * 1024;
    u16* headsb = xh;                     // alias: xh dead after qkv projections

    convert_all_kernel<<<12288, 256, 0, stream>>>(x, wq, wk, wv, w,
                                                  xh, xl, Wth, Wtl, OWth, OWtl);

    dim3 gqk(16, 64);
    qk_mfma_kernel<<<gqk, 256, 0, stream>>>(xh, xl, Wth, Wtl, Qhi, Qlo, Khi, Klo);

    dim3 gv(8, 64);
    v_mfma_kernel<<<gv, 256, 0, stream>>>(xh, Wth, Vt);

    dim3 g2(BH, SEQ / 128);   // bh-major: same-head q-tiles share an XCD
    attn_kernel<<<g2, 512, 0, stream>>>(Qhi, Qlo, Khi, Klo, Vt, headsb);

    dim3 g3(8, 64);
    out_mfma_kernel<<<g3, 256, 0, stream>>>(headsb, OWth, OWtl, out);
}

// Round 8
// 405.815 us; speedup vs baseline: 1.1521x; 1.1521x over previous
//
#include <hip/hip_runtime.h>
#include <hip/hip_bf16.h>
#include <math.h>

#define EMBED 1024
#define KD 64
#define NH 16
#define SEQ 2048
#define BATCH 4
#define BH (BATCH * NH)     // 64
#define NTOK ((size_t)BH * SEQ * KD)   // 8,388,608

typedef float4 f4;
typedef unsigned short u16;
typedef __attribute__((ext_vector_type(8))) short v8s;   // 8 bf16 (MFMA A/B frag)
typedef __attribute__((ext_vector_type(4))) float v4f;   // MFMA C/D frag

__device__ __forceinline__ u16 f2bf(float f) {
    unsigned u = __float_as_uint(f);
    unsigned r = (u + 0x7fffu + ((u >> 16) & 1u)) >> 16;
    return (u16)r;
}
__device__ __forceinline__ float bf2f(u16 h) {
    return __uint_as_float(((unsigned)h) << 16);
}

// async global->LDS, 16B/lane. LDS dest = wave-uniform base + lane*16.
__device__ __forceinline__ void gload_lds16(const void* g, void* l) {
    __builtin_amdgcn_global_load_lds(
        (const __attribute__((address_space(1))) unsigned int*)g,
        (__attribute__((address_space(3))) unsigned int*)l, 16, 0, 0);
}

// ------------------------------------------------------------------
// Fused converter: blocks [0,8192) -> x split; [8192,11264) -> qkv W
// (transposed, Q scaled by 0.125*log2e); [11264,12288) -> out W.
// ------------------------------------------------------------------
__global__ __launch_bounds__(256)
void convert_all_kernel(const float* __restrict__ x,
                        const float* __restrict__ wq, const float* __restrict__ wk,
                        const float* __restrict__ wv, const float* __restrict__ w,
                        u16* __restrict__ xh, u16* __restrict__ xl,
                        u16* __restrict__ Wth, u16* __restrict__ Wtl,
                        u16* __restrict__ OWth, u16* __restrict__ OWtl)
{
    int b = blockIdx.x;
    if (b < 8192) {
        size_t i = ((size_t)b * 256 + threadIdx.x) * 4;
        f4 v = *(const f4*)(x + i);
        u16 h0 = f2bf(v.x), h1 = f2bf(v.y), h2 = f2bf(v.z), h3 = f2bf(v.w);
        u16 l0 = f2bf(v.x - bf2f(h0)), l1 = f2bf(v.y - bf2f(h1));
        u16 l2 = f2bf(v.z - bf2f(h2)), l3 = f2bf(v.w - bf2f(h3));
        uint2 H, L;
        H.x = (unsigned)h0 | ((unsigned)h1 << 16);
        H.y = (unsigned)h2 | ((unsigned)h3 << 16);
        L.x = (unsigned)l0 | ((unsigned)l1 << 16);
        L.y = (unsigned)l2 | ((unsigned)l3 << 16);
        *(uint2*)(xh + i) = H;
        *(uint2*)(xl + i) = L;
    } else if (b < 8192 + 3072) {
        int n = b - 8192;                     // 0..3071
        int mat = n >> 10, nin = n & 1023, h = nin >> 6, c = nin & 63;
        const float* __restrict__ ws = (mat == 0) ? wq : (mat == 1) ? wk : wv;
        float sc = (mat == 0) ? (0.125f * 1.4426950408889634f) : 1.0f;
        for (int d = threadIdx.x; d < EMBED; d += 256) {
            float f = ws[((size_t)h * EMBED + d) * KD + c] * sc;
            u16 hi = f2bf(f);
            u16 lo = f2bf(f - bf2f(hi));
            Wth[(size_t)n * EMBED + d] = hi;
            Wtl[(size_t)n * EMBED + d] = lo;
        }
    } else {
        int n = b - 11264;                    // 0..1023
        for (int k = threadIdx.x; k < EMBED; k += 256) {
            float f = w[(size_t)k * EMBED + n];
            u16 hi = f2bf(f);
            u16 lo = f2bf(f - bf2f(hi));
            OWth[(size_t)n * EMBED + k] = hi;
            OWtl[(size_t)n * EMBED + k] = lo;
        }
    }
}

// ------------------------------------------------------------------
// Kernel: QKV projection, MFMA bf16 — FUSED again (R7): the R3 split
// into qk+v re-staged xh twice and measured +25-30 µs on the non-attn
// side across 5 runs. Fused grid (24,64): n0<2048 -> Q/K (3-term),
// else V (1-term).
// ------------------------------------------------------------------
__global__ __launch_bounds__(256)
void qkv_mfma_kernel(const u16* __restrict__ xh, const u16* __restrict__ xl,
                     const u16* __restrict__ Wth, const u16* __restrict__ Wtl,
                     u16* __restrict__ Qhi, u16* __restrict__ Qlo,
                     u16* __restrict__ Khi, u16* __restrict__ Klo,
                     u16* __restrict__ Vt)
{
    __shared__ u16 sAh[128 * 64];
    __shared__ u16 sAl[128 * 64];
    __shared__ u16 sBh[128 * 64];
    __shared__ u16 sBl[128 * 64];
    const int tid = threadIdx.x;
    const int lane = tid & 63, wid = tid >> 6;
    const int lm = lane & 15, lq = lane >> 4;
    const int wm = wid & 1, wn = wid >> 1;
    const int m0 = blockIdx.y * 128;
    const int n0 = blockIdx.x * 128;
    const bool three = (n0 < 2048);

    v4f acc[4][4];
#pragma unroll
    for (int mt = 0; mt < 4; ++mt)
#pragma unroll
        for (int nt = 0; nt < 4; ++nt)
            acc[mt][nt] = (v4f){0.f, 0.f, 0.f, 0.f};

    const int srow = wid * 32 + (lane >> 3);
    const int sblk = (lane & 7) ^ (lane >> 3);

    for (int k0 = 0; k0 < EMBED; k0 += 64) {
        __syncthreads();
#pragma unroll
        for (int i = 0; i < 4; ++i) {
            int row = srow + i * 8;
            size_t gA = (((size_t)(m0 + row)) << 10) + k0 + sblk * 8;
            size_t gB = (((size_t)(n0 + row)) << 10) + k0 + sblk * 8;
            int lo = (wid * 32 + i * 8) * 128;
            gload_lds16((const char*)xh + gA * 2, (char*)sAh + lo);
            gload_lds16((const char*)Wth + gB * 2, (char*)sBh + lo);
            if (three) {
                gload_lds16((const char*)xl + gA * 2, (char*)sAl + lo);
                gload_lds16((const char*)Wtl + gB * 2, (char*)sBl + lo);
            }
        }
        asm volatile("s_waitcnt vmcnt(0)" ::: "memory");
        __syncthreads();

#pragma unroll
        for (int kks = 0; kks < 2; ++kks) {
            v8s ah[4], bh[4];
            const int ba = ((kks * 4 + lq) ^ (lm & 7)) * 8;
#pragma unroll
            for (int t = 0; t < 4; ++t) {
                int ra = wm * 64 + t * 16 + lm;
                int rb = wn * 64 + t * 16 + lm;
                ah[t] = *(const v8s*)&sAh[ra * 64 + ba];
                bh[t] = *(const v8s*)&sBh[rb * 64 + ba];
            }
            if (three) {
                v8s al[4], bl[4];
#pragma unroll
                for (int t = 0; t < 4; ++t) {
                    int ra = wm * 64 + t * 16 + lm;
                    int rb = wn * 64 + t * 16 + lm;
                    al[t] = *(const v8s*)&sAl[ra * 64 + ba];
                    bl[t] = *(const v8s*)&sBl[rb * 64 + ba];
                }
#pragma unroll
                for (int mt = 0; mt < 4; ++mt)
#pragma unroll
                    for (int nt = 0; nt < 4; ++nt) {
                        acc[mt][nt] = __builtin_amdgcn_mfma_f32_16x16x32_bf16(ah[mt], bh[nt], acc[mt][nt], 0, 0, 0);
                        acc[mt][nt] = __builtin_amdgcn_mfma_f32_16x16x32_bf16(ah[mt], bl[nt], acc[mt][nt], 0, 0, 0);
                        acc[mt][nt] = __builtin_amdgcn_mfma_f32_16x16x32_bf16(al[mt], bh[nt], acc[mt][nt], 0, 0, 0);
                    }
            } else {
#pragma unroll
                for (int mt = 0; mt < 4; ++mt)
#pragma unroll
                    for (int nt = 0; nt < 4; ++nt)
                        acc[mt][nt] = __builtin_amdgcn_mfma_f32_16x16x32_bf16(ah[mt], bh[nt], acc[mt][nt], 0, 0, 0);
            }
        }
    }

    const int mrow0 = m0 + wm * 64;
    const int ncol0 = n0 + wn * 64;
    if (!three) {
#pragma unroll
        for (int mt = 0; mt < 4; ++mt) {
            int sbase = mrow0 + mt * 16 + lq * 4;
            int bb = sbase >> 11, s = sbase & 2047;
#pragma unroll
            for (int nt = 0; nt < 4; ++nt) {
                int nin = (ncol0 + nt * 16 + lm) & 1023;
                int h = nin >> 6, cc = nin & 63;
                int bh_ = bb * NH + h;
                size_t a = ((size_t)bh_ * KD + cc) * SEQ
                         + (size_t)(((((s >> 3) ^ (cc & 7)) << 3)) | (s & 7));
                uint2 u;
                u.x = (unsigned)f2bf(acc[mt][nt][0]) | ((unsigned)f2bf(acc[mt][nt][1]) << 16);
                u.y = (unsigned)f2bf(acc[mt][nt][2]) | ((unsigned)f2bf(acc[mt][nt][3]) << 16);
                *(uint2*)(Vt + a) = u;
            }
        }
    } else {
        const bool isQ = (n0 < 1024);
#pragma unroll
        for (int mt = 0; mt < 4; ++mt) {
            int sbase = mrow0 + mt * 16 + lq * 4;
            int bb = sbase >> 11, sB = sbase & 2047;
#pragma unroll
            for (int nt = 0; nt < 4; ++nt) {
                int nin = (ncol0 + nt * 16 + lm) & 1023;
                int h = nin >> 6, cc = nin & 63;
                int bh_ = bb * NH + h;
#pragma unroll
                for (int r = 0; r < 4; ++r) {
                    int s = sB + r;
                    float f = acc[mt][nt][r];
                    u16 hi = f2bf(f);
                    u16 lo = f2bf(f - bf2f(hi));
                    if (isQ) {
                        size_t a = ((size_t)bh_ * SEQ + s) * KD + cc;
                        Qhi[a] = hi;
                        Qlo[a] = lo;
                    } else {
                        int ccp = ((((cc >> 3) ^ (s & 7)) << 3) | (cc & 7));
                        size_t a = ((size_t)bh_ * SEQ + s) * KD + ccp;
                        Khi[a] = hi;
                        Klo[a] = lo;
                    }
                }
            }
        }
    }
}

// ------------------------------------------------------------------
// Kernel: flash attention, 8-wave, R5 version (best measured: 163.4
// µs). Double-buffered K/V LDS, prefetch-ahead gload_lds, one barrier
// per tile. R6's V-direct-from-global REVERTED: it made each of the 8
// waves load the full 8KB V tile (8x L2 traffic) — attn 163->199 µs.
// V stays LDS-staged (1 DMA/tile, broadcast ds_reads).
// ------------------------------------------------------------------
__global__ __launch_bounds__(512)
void attn_kernel(const u16* __restrict__ Qhi, const u16* __restrict__ Qlo,
                 const u16* __restrict__ Khi, const u16* __restrict__ Klo,
                 const u16* __restrict__ Vt,  u16* __restrict__ headsb)
{
    __shared__ u16 sKV[2][3][64 * 64];   // [buf][Khi,Klo,Vt] 8KB planes
    __shared__ u16 sPs[128 * 64];        // 16 KB; swizzled, wave-private rows

    const int tid = threadIdx.x;
    const int lane = tid & 63, wid = tid >> 6;        // wid 0..7
    const int lm = lane & 15, lq = lane >> 4;
    const int psw = (lm & 7) << 3;   // sPs XOR swizzle (u16 units)
    const int rowbase = (wid >> 1) * 32 + (wid & 1) * 16;   // 0..112, step 16
    const int q0 = blockIdx.y * 128;
    const int bh = blockIdx.x;
    const int bb = bh >> 4, h = bh & 15;

    // Q fragments resident: q-rows q0 + rowbase + lm
    v8s qh[2], ql[2];
#pragma unroll
    for (int kk = 0; kk < 2; ++kk) {
        size_t g = ((size_t)bh * SEQ + q0 + rowbase + lm) * KD + kk * 32 + lq * 8;
        qh[kk] = *(const v8s*)(Qhi + g);
        ql[kk] = *(const v8s*)(Qlo + g);
    }

    v8s vones;
#pragma unroll
    for (int i = 0; i < 8; ++i) vones[i] = (short)0x3F80;   // bf16 1.0
    const v4f z4 = (v4f){0.f, 0.f, 0.f, 0.f};               // hoisted zero C

    // bpermute source-lane addrs: alpha for ctx row lq*4+r lives at lane
    // (same lq group) with lm = lq*4+r
    int bpaddr[4];
#pragma unroll
    for (int r = 0; r < 4; ++r)
        bpaddr[r] = (((lane & 48) | (lq * 4 + r)) << 2);

    v4f ctx[4], lcol;
    float mrun = -INFINITY;
    lcol = (v4f){0.f, 0.f, 0.f, 0.f};
#pragma unroll
    for (int nt = 0; nt < 4; ++nt)
        ctx[nt] = (v4f){0.f, 0.f, 0.f, 0.f};

    const size_t kbase = (size_t)bh * SEQ * KD;
    const char* gKh = (const char*)(Khi + kbase);
    const char* gKl = (const char*)(Klo + kbase);
    const int ko = wid * 1024;                      // LDS byte offset per wave
    // V rows (hd dim): wave stages rows wid*8 .. wid*8+7
    const char* gV = (const char*)(Vt + ((size_t)bh * KD + wid * 8 + (lane >> 3)) * SEQ)
                   + (lane & 7) * 16;

    // stage key-tile starting at key t0 into buffer buf
    auto STAGE = [&](int t0, int buf) {
        int kb = t0 * 128 + ko + lane * 16;         // K bytes (128B per key row)
        gload_lds16(gKh + kb, (char*)sKV[buf][0] + ko);
        gload_lds16(gKl + kb, (char*)sKV[buf][1] + ko);
        gload_lds16(gV + t0 * 2, (char*)sKV[buf][2] + ko);
    };

    STAGE(0, 0);

    int cur = 0;
    for (int t0 = 0; t0 < SEQ; t0 += 64, cur ^= 1) {
        asm volatile("s_waitcnt vmcnt(0)" ::: "memory");   // own tile-t loads done
        __syncthreads();                                    // all waves' loads done;
                                                            // all reads of buf^1 done
        if (t0 + 64 < SEQ) STAGE(t0 + 64, cur ^ 1);         // async prefetch, no wait
        const u16* sKhi = sKV[cur][0];
        const u16* sKlo = sKV[cur][1];
        const u16* sVt  = sKV[cur][2];

        // ---- scores = K·Q^T: sc[kt], rows=keys, cols=qrows (this wave's group)
        v4f sc[4];
        __builtin_amdgcn_s_setprio(1);
#pragma unroll
        for (int kt = 0; kt < 4; ++kt) {
            int key = kt * 16 + lm;
            int blk = lq ^ (key & 7);                 // kk = 0
            v8s kh16 = *(const v8s*)&sKhi[key * 64 + blk * 8];
            v8s kl16 = *(const v8s*)&sKlo[key * 64 + blk * 8];
            sc[kt] = __builtin_amdgcn_mfma_f32_16x16x32_bf16(kh16, qh[0], z4, 0, 0, 0);
            sc[kt] = __builtin_amdgcn_mfma_f32_16x16x32_bf16(kl16, qh[0], sc[kt], 0, 0, 0);
            sc[kt] = __builtin_amdgcn_mfma_f32_16x16x32_bf16(kh16, ql[0], sc[kt], 0, 0, 0);
        }
#pragma unroll
        for (int kt = 0; kt < 4; ++kt) {
            int key = kt * 16 + lm;
            int blk = (4 + lq) ^ (key & 7);           // kk = 1
            v8s kh16 = *(const v8s*)&sKhi[key * 64 + blk * 8];
            v8s kl16 = *(const v8s*)&sKlo[key * 64 + blk * 8];
            sc[kt] = __builtin_amdgcn_mfma_f32_16x16x32_bf16(kh16, qh[1], sc[kt], 0, 0, 0);
            sc[kt] = __builtin_amdgcn_mfma_f32_16x16x32_bf16(kl16, qh[1], sc[kt], 0, 0, 0);
            sc[kt] = __builtin_amdgcn_mfma_f32_16x16x32_bf16(kh16, ql[1], sc[kt], 0, 0, 0);
        }
        __builtin_amdgcn_s_setprio(0);

        // ---- online softmax (base-2): lane owns q-row lm; 16 vals =
        // keys kt*16 + lq*4 + r
        float m0v = fmaxf(fmaxf(fmaxf(sc[0][0], sc[0][1]), sc[0][2]), sc[0][3]);
        float m1v = fmaxf(fmaxf(fmaxf(sc[1][0], sc[1][1]), sc[1][2]), sc[1][3]);
        float m2v = fmaxf(fmaxf(fmaxf(sc[2][0], sc[2][1]), sc[2][2]), sc[2][3]);
        float m3v = fmaxf(fmaxf(fmaxf(sc[3][0], sc[3][1]), sc[3][2]), sc[3][3]);
        float mx = fmaxf(fmaxf(fmaxf(m0v, m1v), m2v), m3v);
        mx = fmaxf(mx, __shfl_xor(mx, 16));
        mx = fmaxf(mx, __shfl_xor(mx, 32));

        // ---- T13 defer-max: skip rescale when nothing grew past mrun+8.
        if (!__all((int)(mx <= mrun + 8.f))) {
            float mold = mrun;
            float mnew = fmaxf(mold, mx);
            float a = __builtin_amdgcn_exp2f(mold - mnew);
            mrun = mnew;
#pragma unroll
            for (int r = 0; r < 4; ++r) {
                float ar = __uint_as_float(
                    __builtin_amdgcn_ds_bpermute(bpaddr[r], __float_as_uint(a)));
                lcol[r] *= ar;
#pragma unroll
                for (int nt = 0; nt < 4; ++nt)
                    ctx[nt][r] *= ar;
            }
        }

        // ---- p, truncate-pack, b64 write: 4 consecutive keys per quad
        {
            u16* pbase = &sPs[(rowbase + lm) * 64];
#pragma unroll
            for (int kt = 0; kt < 4; ++kt) {
                unsigned u0 = __float_as_uint(__builtin_amdgcn_exp2f(sc[kt][0] - mrun));
                unsigned u1 = __float_as_uint(__builtin_amdgcn_exp2f(sc[kt][1] - mrun));
                unsigned u2 = __float_as_uint(__builtin_amdgcn_exp2f(sc[kt][2] - mrun));
                unsigned u3 = __float_as_uint(__builtin_amdgcn_exp2f(sc[kt][3] - mrun));
                uint2 pk;
                pk.x = __builtin_amdgcn_perm(u1, u0, 0x07060302);  // [bf(p1)|bf(p0)]
                pk.y = __builtin_amdgcn_perm(u3, u2, 0x07060302);
                *(uint2*)&pbase[(kt * 16 + lq * 4) ^ psw] = pk;
            }
        }
        // same-wave ds_write -> ds_read (compiler inserts lgkm wait);
        // P rows are wave-private, no barrier needed.

        // ---- PV (+ ones column accumulates l)
        __builtin_amdgcn_s_setprio(1);
#pragma unroll
        for (int kk2 = 0; kk2 < 2; ++kk2) {
            v8s a = *(const v8s*)&sPs[(rowbase + lm) * 64 + ((kk2 * 32 + lq * 8) ^ psw)];
#pragma unroll
            for (int nt = 0; nt < 4; ++nt) {
                int hd = nt * 16 + lm;
                int blk = (kk2 * 4 + lq) ^ (hd & 7);
                v8s b = *(const v8s*)&sVt[hd * 64 + blk * 8];
                ctx[nt] = __builtin_amdgcn_mfma_f32_16x16x32_bf16(a, b, ctx[nt], 0, 0, 0);
            }
            lcol = __builtin_amdgcn_mfma_f32_16x16x32_bf16(a, vones, lcol, 0, 0, 0);
        }
        __builtin_amdgcn_s_setprio(0);
    }

    // ---- epilogue: heads[bb][row][h*64+hd] = ctx / l (bf16)
#pragma unroll
    for (int r = 0; r < 4; ++r) {
        int row = q0 + rowbase + lq * 4 + r;
        float inv = 1.0f / lcol[r];
        u16* dst = headsb + ((size_t)bb * SEQ + row) * EMBED + h * KD;
#pragma unroll
        for (int nt = 0; nt < 4; ++nt)
            dst[nt * 16 + lm] = f2bf(ctx[nt][r] * inv);
    }
}

// ------------------------------------------------------------------
// Kernel: output projection, MFMA bf16 2-term (unchanged).
// ------------------------------------------------------------------
__global__ __launch_bounds__(256)
void out_mfma_kernel(const u16* __restrict__ headsb,
                     const u16* __restrict__ OWth, const u16* __restrict__ OWtl,
                     float* __restrict__ out)
{
    __shared__ u16 sA[128 * 64];
    __shared__ u16 sBh[128 * 64];
    __shared__ u16 sBl[128 * 64];
    const int tid = threadIdx.x;
    const int lane = tid & 63, wid = tid >> 6;
    const int lm = lane & 15, lq = lane >> 4;
    const int wm = wid & 1, wn = wid >> 1;
    const int m0 = blockIdx.y * 128;
    const int n0 = blockIdx.x * 128;

    v4f acc[4][4];
#pragma unroll
    for (int mt = 0; mt < 4; ++mt)
#pragma unroll
        for (int nt = 0; nt < 4; ++nt)
            acc[mt][nt] = (v4f){0.f, 0.f, 0.f, 0.f};

    const int srow = wid * 32 + (lane >> 3);
    const int sblk = (lane & 7) ^ (lane >> 3);

    for (int k0 = 0; k0 < EMBED; k0 += 64) {
        __syncthreads();
#pragma unroll
        for (int i = 0; i < 4; ++i) {
            int row = srow + i * 8;
            size_t gA = (((size_t)(m0 + row)) << 10) + k0 + sblk * 8;
            size_t gB = (((size_t)(n0 + row)) << 10) + k0 + sblk * 8;
            int lo = (wid * 32 + i * 8) * 128;
            gload_lds16((const char*)headsb + gA * 2, (char*)sA + lo);
            gload_lds16((const char*)OWth + gB * 2, (char*)sBh + lo);
            gload_lds16((const char*)OWtl + gB * 2, (char*)sBl + lo);
        }
        asm volatile("s_waitcnt vmcnt(0)" ::: "memory");
        __syncthreads();

#pragma unroll
        for (int kks = 0; kks < 2; ++kks) {
            const int ba = ((kks * 4 + lq) ^ (lm & 7)) * 8;
            v8s ah[4], bh[4], bl[4];
#pragma unroll
            for (int t = 0; t < 4; ++t) {
                int ra = wm * 64 + t * 16 + lm;
                int rb = wn * 64 + t * 16 + lm;
                ah[t] = *(const v8s*)&sA[ra * 64 + ba];
                bh[t] = *(const v8s*)&sBh[rb * 64 + ba];
                bl[t] = *(const v8s*)&sBl[rb * 64 + ba];
            }
#pragma unroll
            for (int mt = 0; mt < 4; ++mt)
#pragma unroll
                for (int nt = 0; nt < 4; ++nt) {
                    acc[mt][nt] = __builtin_amdgcn_mfma_f32_16x16x32_bf16(ah[mt], bh[nt], acc[mt][nt], 0, 0, 0);
                    acc[mt][nt] = __builtin_amdgcn_mfma_f32_16x16x32_bf16(ah[mt], bl[nt], acc[mt][nt], 0, 0, 0);
                }
        }
    }

    const int mrow0 = m0 + wm * 64;
    const int ncol0 = n0 + wn * 64;
#pragma unroll
    for (int mt = 0; mt < 4; ++mt) {
        int sbase = mrow0 + mt * 16 + lq * 4;
#pragma unroll
        for (int nt = 0; nt < 4; ++nt) {
            int n = ncol0 + nt * 16 + lm;
#pragma unroll
            for (int r = 0; r < 4; ++r)
                out[(size_t)(sbase + r) * EMBED + n] = acc[mt][nt][r];
        }
    }
}

// ------------------------------------------------------------------
extern "C" void kernel_launch(void* const* d_in, const int* in_sizes, int n_in,
                              void* d_out, int out_size, void* d_ws, size_t ws_size,
                              hipStream_t stream) {
    const float* x  = (const float*)d_in[0];
    const float* wq = (const float*)d_in[1];
    const float* wk = (const float*)d_in[2];
    const float* wv = (const float*)d_in[3];
    const float* w  = (const float*)d_in[4];
    float* out = (float*)d_out;

    u16* Qhi = (u16*)d_ws;
    u16* Qlo = Qhi + NTOK;
    u16* Khi = Qlo + NTOK;
    u16* Klo = Khi + NTOK;
    u16* Vt  = Klo + NTOK;
    u16* xh  = Vt + NTOK;                 // [8192][1024]
    u16* xl  = xh + NTOK;
    u16* Wth = xl + NTOK;                 // [3072][1024]
    u16* Wtl = Wth + (size_t)3072 * 1024;
    u16* OWth = Wtl + (size_t)3072 * 1024;  // [1024][1024]
    u16* OWtl = OWth + (size_t)1024 * 1024;
    u16* headsb = xh;                     // alias: xh dead after qkv_mfma

    convert_all_kernel<<<12288, 256, 0, stream>>>(x, wq, wk, wv, w,
                                                  xh, xl, Wth, Wtl, OWth, OWtl);

    dim3 g1(24, 64);
    qkv_mfma_kernel<<<g1, 256, 0, stream>>>(xh, xl, Wth, Wtl, Qhi, Qlo, Khi, Klo, Vt);

    dim3 g2(BH, SEQ / 128);   // bh-major: same-head q-tiles share an XCD
    attn_kernel<<<g2, 512, 0, stream>>>(Qhi, Qlo, Khi, Klo, Vt, headsb);

    dim3 g3(8, 64);
    out_mfma_kernel<<<g3, 256, 0, stream>>>(headsb, OWth, OWtl, out);
}